// Round 6
// baseline (745.593 us; speedup 1.0000x reference)
//
#include <hip/hip_runtime.h>

#define CPC 2000          // max candidates per class
#define SPC 100           // max survivors per class
#define NCLS 90
#define TM 128
#define TN 128
#define TKK 16

typedef __attribute__((ext_vector_type(8))) short bf16x8;
typedef __attribute__((ext_vector_type(4))) float f32x4;
typedef __attribute__((ext_vector_type(4))) unsigned short u16x4;

// ---------------- helpers ----------------
__device__ __forceinline__ unsigned short f2bf_rne(float f) {
    unsigned u = __float_as_uint(f);
    return (unsigned short)((u + 0x7FFFu + ((u >> 16) & 1u)) >> 16);
}
__device__ __forceinline__ unsigned short f2bf_trunc(float f) {
    return (unsigned short)(__float_as_uint(f) >> 16);
}
__device__ __forceinline__ float bfhi_f32(float f) {
    return __uint_as_float(__float_as_uint(f) & 0xFFFF0000u);
}
__device__ __forceinline__ void async_load16(const void* g, void* l) {
    __builtin_amdgcn_global_load_lds((const __attribute__((address_space(1))) unsigned int*)g,
                                     (__attribute__((address_space(3))) unsigned int*)l, 16, 0, 0);
}
// XOR swizzle on 16B-chunk index (involution; same on write/source and read)
__device__ __forceinline__ int swz(int c) { return c ^ ((c >> 3) & 3); }

__device__ __forceinline__ void split8(const float* f, bf16x8& hi, bf16x8& lo) {
#pragma unroll
    for (int e = 0; e < 8; ++e) {
        hi[e] = (short)f2bf_trunc(f[e]);
        lo[e] = (short)f2bf_rne(f[e] - bfhi_f32(f[e]));
    }
}

// XCD-aware block remap (T1): bijective when nwg%8==0; contiguous chunk per XCD.
__device__ __forceinline__ void xcd_remap(unsigned& bx, unsigned& by, unsigned& bz)
{
    const unsigned nx = gridDim.x, ny = gridDim.y;
    const unsigned nwg = nx * ny * gridDim.z;
    unsigned lin = blockIdx.x + nx * (blockIdx.y + ny * blockIdx.z);
    if ((nwg & 7u) == 0u)
        lin = (lin & 7u) * (nwg >> 3) + (lin >> 3);
    bx = lin % nx;
    unsigned rem = lin / nx;
    by = rem % ny;
    bz = rem / ny;
}

// ---- shared GEMM building blocks (compile-time LDS bases via forceinline args) ----
__device__ __forceinline__ void stage_b(
    const unsigned short* __restrict__ Bhi, const unsigned short* __restrict__ Blo,
    unsigned bsrc0, unsigned bsrc1, int ks, int wv,
    unsigned short* BhB, unsigned short* BlB)
{
    async_load16(Bhi + bsrc0 + ks, &BhB[(wv * 64) * 8]);
    async_load16(Blo + bsrc0 + ks, &BlB[(wv * 64) * 8]);
    async_load16(Bhi + bsrc1 + ks, &BhB[(256 + wv * 64) * 8]);
    async_load16(Blo + bsrc1 + ks, &BlB[(256 + wv * 64) * 8]);
}

__device__ __forceinline__ void mfma_tile(
    const unsigned short* __restrict__ AhB, const unsigned short* __restrict__ AlB,
    const unsigned short* __restrict__ BhB, const unsigned short* __restrict__ BlB,
    int lm, int q, int bcol_t, f32x4 (&acc)[4][2])
{
    bf16x8 afh[4], afl[4], bfh[2], bfl[2];
#pragma unroll
    for (int mi = 0; mi < 4; ++mi) {
        int p = swz((mi * 16 + lm) * 4 + q);
        afh[mi] = *(const bf16x8*)&AhB[p * 8];
        afl[mi] = *(const bf16x8*)&AlB[p * 8];
    }
#pragma unroll
    for (int ni = 0; ni < 2; ++ni) {
        int p = swz((bcol_t + ni * 16 + lm) * 4 + q);
        bfh[ni] = *(const bf16x8*)&BhB[p * 8];
        bfl[ni] = *(const bf16x8*)&BlB[p * 8];
    }
#pragma unroll
    for (int mi = 0; mi < 4; ++mi)
#pragma unroll
        for (int ni = 0; ni < 2; ++ni) {
            acc[mi][ni] = __builtin_amdgcn_mfma_f32_16x16x32_bf16(afh[mi], bfh[ni], acc[mi][ni], 0, 0, 0);
            acc[mi][ni] = __builtin_amdgcn_mfma_f32_16x16x32_bf16(afl[mi], bfh[ni], acc[mi][ni], 0, 0, 0);
            acc[mi][ni] = __builtin_amdgcn_mfma_f32_16x16x32_bf16(afh[mi], bfl[ni], acc[mi][ni], 0, 0, 0);
        }
}

// ---------------- split + transpose: W[K][N] fp32 -> Thi/Tlo [N][K] bf16 --------------
__global__ __launch_bounds__(256) void split_transpose(
    const float* __restrict__ W, unsigned short* __restrict__ Thi,
    unsigned short* __restrict__ Tlo, int K, int N)
{
    __shared__ float tile[64][33];
    const int kt = blockIdx.x * 64, nt = blockIdx.y * 32;
    const int tx = threadIdx.x & 31, ty = threadIdx.x >> 5;
#pragma unroll
    for (int j = 0; j < 8; ++j) {
        int k = kt + ty + j * 8, n = nt + tx;
        tile[ty + j * 8][tx] = (k < K && n < N) ? W[(size_t)k * N + n] : 0.f;
    }
    __syncthreads();
#pragma unroll
    for (int j = 0; j < 4; ++j) {
        int n = nt + ty + j * 8;
        int k = kt + tx * 2;
        if (n < N && k < K) {
            float f0 = tile[tx * 2][ty + j * 8];
            float f1 = tile[tx * 2 + 1][ty + j * 8];
            unsigned hi = (unsigned)f2bf_trunc(f0) | ((unsigned)f2bf_trunc(f1) << 16);
            unsigned lo = (unsigned)f2bf_rne(f0 - bfhi_f32(f0))
                        | ((unsigned)f2bf_rne(f1 - bfhi_f32(f1)) << 16);
            *reinterpret_cast<unsigned*>(&Thi[(size_t)n * K + k]) = hi;
            *reinterpret_cast<unsigned*>(&Tlo[(size_t)n * K + k]) = lo;
        }
    }
}

// dual-source variant: output row n<Na from Wa col n, else Wb col n-Na (heads fusion)
__global__ __launch_bounds__(256) void split_transpose2(
    const float* __restrict__ Wa, const float* __restrict__ Wb, int Na, int Nb,
    unsigned short* __restrict__ Thi, unsigned short* __restrict__ Tlo, int K)
{
    const int N = Na + Nb;
    __shared__ float tile[64][33];
    const int kt = blockIdx.x * 64, nt = blockIdx.y * 32;
    const int tx = threadIdx.x & 31, ty = threadIdx.x >> 5;
#pragma unroll
    for (int j = 0; j < 8; ++j) {
        int k = kt + ty + j * 8, n = nt + tx;
        float v = 0.f;
        if (k < K && n < N)
            v = (n < Na) ? Wa[(size_t)k * Na + n] : Wb[(size_t)k * Nb + (n - Na)];
        tile[ty + j * 8][tx] = v;
    }
    __syncthreads();
#pragma unroll
    for (int j = 0; j < 4; ++j) {
        int n = nt + ty + j * 8;
        int k = kt + tx * 2;
        if (n < N && k < K) {
            float f0 = tile[tx * 2][ty + j * 8];
            float f1 = tile[tx * 2 + 1][ty + j * 8];
            unsigned hi = (unsigned)f2bf_trunc(f0) | ((unsigned)f2bf_trunc(f1) << 16);
            unsigned lo = (unsigned)f2bf_rne(f0 - bfhi_f32(f0))
                        | ((unsigned)f2bf_rne(f1 - bfhi_f32(f1)) << 16);
            *reinterpret_cast<unsigned*>(&Thi[(size_t)n * K + k]) = hi;
            *reinterpret_cast<unsigned*>(&Tlo[(size_t)n * K + k]) = lo;
        }
    }
}

// ---------------- bf16x3 MFMA GEMM, 64x128 tile, fp32 A split on the fly --------------
// Prefetch @ 4 blocks/CU: B double-buffered via global_load_lds (stage t+1 issued
// BEFORE compute t -> vmcnt drain at barrier lands after the compute window);
// A register-carried (T14), split + ds_write between the two barriers.
// 2x-unrolled so all global_load_lds LDS destinations are compile-time (R3-proven).
// LDS 40 KB -> 4 blocks/CU.
__global__ __launch_bounds__(256, 4) void gemm_bf16x3_f32a(
    const float* __restrict__ A, const unsigned short* __restrict__ Bhi,
    const unsigned short* __restrict__ Blo, float* __restrict__ C,
    int M, int N, int K, int klen)      // klen multiple of 32
{
    __shared__ unsigned short Ah[2048], Al[2048];          // 8 KB (single)
    __shared__ unsigned short Bh[2][4096], Bl[2][4096];    // 32 KB (dbuf)
    unsigned bxu, byu, bzu;
    xcd_remap(bxu, byu, bzu);
    const int tid = threadIdx.x;
    const int wv = tid >> 6, ln = tid & 63;
    const int q = ln >> 4, lm = ln & 15;
    const int m0 = byu * 64, n0 = bxu * 128;
    const int k0 = bzu * klen;
    int k1 = k0 + klen; if (k1 > K) k1 = K;
    const int bcol_t = wv * 32;

    f32x4 acc[4][2];
#pragma unroll
    for (int i = 0; i < 4; ++i)
#pragma unroll
        for (int j = 0; j < 2; ++j) acc[i][j] = (f32x4)0.f;

    // A staging: thread t = logical chunk t (row t>>2, k-octet t&3), physical swz(t)
    int gr = m0 + (tid >> 2); if (gr >= M) gr = M - 1;     // clamp: dup read, never stored
    const float* Arow = A + (size_t)gr * K + (tid & 3) * 8;
    const int apc = swz(tid);

    // B staging: slot s holds logical chunk swz(s): col = s>>2, octet = (s&3)^((s>>3)&3)
    unsigned bsrc0, bsrc1;
    {
        int s0 = tid;
        int gn0 = n0 + (s0 >> 2); if (gn0 >= N) gn0 = N - 1;
        bsrc0 = (unsigned)gn0 * (unsigned)K + (unsigned)(((s0 & 3) ^ ((s0 >> 3) & 3)) * 8);
        int s1 = 256 + tid;
        int gn1 = n0 + (s1 >> 2); if (gn1 >= N) gn1 = N - 1;
        bsrc1 = (unsigned)gn1 * (unsigned)K + (unsigned)(((s1 & 3) ^ ((s1 >> 3) & 3)) * 8);
    }

    // ---- prologue: tile k0 ----
    float f[8];
    {
        float4 v0 = *reinterpret_cast<const float4*>(Arow + k0);
        float4 v1 = *reinterpret_cast<const float4*>(Arow + k0 + 4);
        f[0] = v0.x; f[1] = v0.y; f[2] = v0.z; f[3] = v0.w;
        f[4] = v1.x; f[5] = v1.y; f[6] = v1.z; f[7] = v1.w;
    }
    stage_b(Bhi, Blo, bsrc0, bsrc1, k0, wv, Bh[0], Bl[0]);
    {
        bf16x8 hi, lo;
        split8(f, hi, lo);
        *(bf16x8*)&Ah[apc * 8] = hi;
        *(bf16x8*)&Al[apc * 8] = lo;
    }
    __syncthreads();

    int kt = k0;
    for (;;) {
        // ---- phase 0: compute from buf0, prefetch t+1 into buf1 ----
        const bool n1 = kt + 32 < k1;
        if (n1) {
            // A regs first (older vmcnt slots), then B stage
            float4 v0 = *reinterpret_cast<const float4*>(Arow + kt + 32);
            float4 v1 = *reinterpret_cast<const float4*>(Arow + kt + 36);
            f[0] = v0.x; f[1] = v0.y; f[2] = v0.z; f[3] = v0.w;
            f[4] = v1.x; f[5] = v1.y; f[6] = v1.z; f[7] = v1.w;
            stage_b(Bhi, Blo, bsrc0, bsrc1, kt + 32, wv, Bh[1], Bl[1]);
        }
        mfma_tile(Ah, Al, Bh[0], Bl[0], lm, q, bcol_t, acc);
        __syncthreads();               // readers of Ah/Al & buf0 done; drains vmcnt AFTER compute
        if (n1) {
            bf16x8 hi, lo;
            split8(f, hi, lo);
            *(bf16x8*)&Ah[apc * 8] = hi;
            *(bf16x8*)&Al[apc * 8] = lo;
        }
        __syncthreads();               // A(t+1) visible
        if (!n1) break;
        // ---- phase 1: compute from buf1, prefetch t+2 into buf0 ----
        const bool n2 = kt + 64 < k1;
        if (n2) {
            float4 v0 = *reinterpret_cast<const float4*>(Arow + kt + 64);
            float4 v1 = *reinterpret_cast<const float4*>(Arow + kt + 68);
            f[0] = v0.x; f[1] = v0.y; f[2] = v0.z; f[3] = v0.w;
            f[4] = v1.x; f[5] = v1.y; f[6] = v1.z; f[7] = v1.w;
            stage_b(Bhi, Blo, bsrc0, bsrc1, kt + 64, wv, Bh[0], Bl[0]);
        }
        mfma_tile(Ah, Al, Bh[1], Bl[1], lm, q, bcol_t, acc);
        __syncthreads();
        if (n2) {
            bf16x8 hi, lo;
            split8(f, hi, lo);
            *(bf16x8*)&Ah[apc * 8] = hi;
            *(bf16x8*)&Al[apc * 8] = lo;
        }
        __syncthreads();
        if (!n2) break;
        kt += 64;
    }

    // ---- store partials: C/D layout row=q*4+ri, col=lm
    float* Cz = C + (size_t)bzu * (size_t)M * (size_t)N;
#pragma unroll
    for (int mi = 0; mi < 4; ++mi)
#pragma unroll
        for (int ni = 0; ni < 2; ++ni)
#pragma unroll
            for (int ri = 0; ri < 4; ++ri) {
                int rr = m0 + mi * 16 + q * 4 + ri;
                int cc = n0 + bcol_t + ni * 16 + lm;
                if (rr < M && cc < N) Cz[(size_t)rr * N + cc] = acc[mi][ni][ri];
            }
}

// ---------------- bf16x3 MFMA GEMM, 64x128 tile, pre-split A (prefetch variant) -------
__global__ __launch_bounds__(256, 4) void gemm_bf16x3_sa(
    const unsigned short* __restrict__ Ahi_g, const unsigned short* __restrict__ Alo_g,
    const unsigned short* __restrict__ Bhi, const unsigned short* __restrict__ Blo,
    float* __restrict__ C, int M, int N, int K, int klen)
{
    __shared__ unsigned short Ah[2048], Al[2048];          // 8 KB (single)
    __shared__ unsigned short Bh[2][4096], Bl[2][4096];    // 32 KB (dbuf)
    unsigned bxu, byu, bzu;
    xcd_remap(bxu, byu, bzu);
    const int tid = threadIdx.x;
    const int wv = tid >> 6, ln = tid & 63;
    const int q = ln >> 4, lm = ln & 15;
    const int m0 = byu * 64, n0 = bxu * 128;
    const int k0 = bzu * klen;
    int k1 = k0 + klen; if (k1 > K) k1 = K;
    const int bcol_t = wv * 32;

    f32x4 acc[4][2];
#pragma unroll
    for (int i = 0; i < 4; ++i)
#pragma unroll
        for (int j = 0; j < 2; ++j) acc[i][j] = (f32x4)0.f;

    // A reg-staging: thread t = logical chunk t (row t>>2, octet t&3), physical swz(t)
    int agr = m0 + (tid >> 2); if (agr >= M) agr = M - 1;
    const unsigned asrc = (unsigned)agr * (unsigned)K + (unsigned)((tid & 3) * 8);
    const int apc = swz(tid);

    unsigned bsrc0, bsrc1;
    {
        int s0 = tid;
        int gn0 = n0 + (s0 >> 2); if (gn0 >= N) gn0 = N - 1;
        bsrc0 = (unsigned)gn0 * (unsigned)K + (unsigned)(((s0 & 3) ^ ((s0 >> 3) & 3)) * 8);
        int s1 = 256 + tid;
        int gn1 = n0 + (s1 >> 2); if (gn1 >= N) gn1 = N - 1;
        bsrc1 = (unsigned)gn1 * (unsigned)K + (unsigned)(((s1 & 3) ^ ((s1 >> 3) & 3)) * 8);
    }

    // ---- prologue ----
    bf16x8 ahr = *(const bf16x8*)(Ahi_g + asrc + k0);
    bf16x8 alr = *(const bf16x8*)(Alo_g + asrc + k0);
    stage_b(Bhi, Blo, bsrc0, bsrc1, k0, wv, Bh[0], Bl[0]);
    *(bf16x8*)&Ah[apc * 8] = ahr;
    *(bf16x8*)&Al[apc * 8] = alr;
    __syncthreads();

    int kt = k0;
    for (;;) {
        const bool n1 = kt + 32 < k1;
        if (n1) {
            ahr = *(const bf16x8*)(Ahi_g + asrc + kt + 32);
            alr = *(const bf16x8*)(Alo_g + asrc + kt + 32);
            stage_b(Bhi, Blo, bsrc0, bsrc1, kt + 32, wv, Bh[1], Bl[1]);
        }
        mfma_tile(Ah, Al, Bh[0], Bl[0], lm, q, bcol_t, acc);
        __syncthreads();
        if (n1) {
            *(bf16x8*)&Ah[apc * 8] = ahr;
            *(bf16x8*)&Al[apc * 8] = alr;
        }
        __syncthreads();
        if (!n1) break;
        const bool n2 = kt + 64 < k1;
        if (n2) {
            ahr = *(const bf16x8*)(Ahi_g + asrc + kt + 64);
            alr = *(const bf16x8*)(Alo_g + asrc + kt + 64);
            stage_b(Bhi, Blo, bsrc0, bsrc1, kt + 64, wv, Bh[0], Bl[0]);
        }
        mfma_tile(Ah, Al, Bh[1], Bl[1], lm, q, bcol_t, acc);
        __syncthreads();
        if (n2) {
            *(bf16x8*)&Ah[apc * 8] = ahr;
            *(bf16x8*)&Al[apc * 8] = alr;
        }
        __syncthreads();
        if (!n2) break;
        kt += 64;
    }

    float* Cz = C + (size_t)bzu * (size_t)M * (size_t)N;
#pragma unroll
    for (int mi = 0; mi < 4; ++mi)
#pragma unroll
        for (int ni = 0; ni < 2; ++ni)
#pragma unroll
            for (int ri = 0; ri < 4; ++ri) {
                int rr = m0 + mi * 16 + q * 4 + ri;
                int cc = n0 + bcol_t + ni * 16 + lm;
                if (rr < M && cc < N) Cz[(size_t)rr * N + cc] = acc[mi][ni][ri];
            }
}

// ---------------- fp32 vector GEMM (fallback path only) ----------------
__global__ __launch_bounds__(256) void gemm_f32(
    const float* __restrict__ A, const float* __restrict__ B,
    const float* __restrict__ bias, float* __restrict__ C,
    int M, int N, int K, int ksplit, int relu)
{
    __shared__ float As[TKK][TM + 4];
    __shared__ float Bs[TKK][TN + 4];
    const int tid = threadIdx.x;
    const int tx = tid & 15, ty = tid >> 4;
    const int m0 = blockIdx.y * TM, n0 = blockIdx.x * TN;
    const int z = blockIdx.z;
    const int kstart = z * ksplit;
    const int kend = (kstart + ksplit < K) ? (kstart + ksplit) : K;
    float* Cz = C + (size_t)z * (size_t)M * (size_t)N;
    const bool nvec = ((N & 3) == 0);

    float acc[8][8];
#pragma unroll
    for (int i = 0; i < 8; ++i)
#pragma unroll
        for (int j = 0; j < 8; ++j) acc[i][j] = 0.f;

    for (int kt = kstart; kt < kend; kt += TKK) {
#pragma unroll
        for (int l = 0; l < 2; ++l) {
            int idx = tid + l * 256;
            int rr = idx >> 2, kq = idx & 3;
            float4 v = make_float4(0.f, 0.f, 0.f, 0.f);
            int grr = m0 + rr;
            if (grr < M)
                v = *reinterpret_cast<const float4*>(A + (size_t)grr * K + kt + (kq << 2));
            As[(kq << 2) + 0][rr] = v.x;
            As[(kq << 2) + 1][rr] = v.y;
            As[(kq << 2) + 2][rr] = v.z;
            As[(kq << 2) + 3][rr] = v.w;
        }
#pragma unroll
        for (int l = 0; l < 2; ++l) {
            int idx = tid + l * 256;
            int kk = idx >> 5, nq = idx & 31;
            int gn = n0 + (nq << 2);
            const float* bp = B + (size_t)(kt + kk) * N + gn;
            float4 v;
            if (nvec && gn + 3 < N) {
                v = *reinterpret_cast<const float4*>(bp);
            } else {
                v.x = (gn + 0 < N) ? bp[0] : 0.f;
                v.y = (gn + 1 < N) ? bp[1] : 0.f;
                v.z = (gn + 2 < N) ? bp[2] : 0.f;
                v.w = (gn + 3 < N) ? bp[3] : 0.f;
            }
            *reinterpret_cast<float4*>(&Bs[kk][nq << 2]) = v;
        }
        __syncthreads();
#pragma unroll
        for (int kk = 0; kk < TKK; ++kk) {
            float a[8], b[8];
            *reinterpret_cast<float4*>(&a[0]) = *reinterpret_cast<const float4*>(&As[kk][ty * 8]);
            *reinterpret_cast<float4*>(&a[4]) = *reinterpret_cast<const float4*>(&As[kk][ty * 8 + 4]);
            *reinterpret_cast<float4*>(&b[0]) = *reinterpret_cast<const float4*>(&Bs[kk][tx * 4]);
            *reinterpret_cast<float4*>(&b[4]) = *reinterpret_cast<const float4*>(&Bs[kk][64 + tx * 4]);
#pragma unroll
            for (int i = 0; i < 8; ++i)
#pragma unroll
                for (int j = 0; j < 8; ++j)
                    acc[i][j] = fmaf(a[i], b[j], acc[i][j]);
        }
        __syncthreads();
    }
#pragma unroll
    for (int i = 0; i < 8; ++i) {
        int grr = m0 + ty * 8 + i;
        if (grr >= M) continue;
#pragma unroll
        for (int j = 0; j < 8; ++j) {
            int gc = n0 + ((j < 4) ? (tx * 4 + j) : (64 + tx * 4 + (j - 4)));
            if (gc >= N) continue;
            float v = acc[i][j];
            if (bias) v += bias[gc];
            if (relu) v = fmaxf(v, 0.f);
            Cz[(size_t)grr * N + gc] = v;
        }
    }
}

// ---------------- combine split-K partials + bias (+relu), fp32 out (fallback) --------
__global__ void combine_bias_act(const float* __restrict__ P, const float* __restrict__ bias,
                                 float* __restrict__ H, int total, int N, int nsplit,
                                 int pstride, int relu)
{
    int i = blockIdx.x * blockDim.x + threadIdx.x;
    if (i >= total) return;
    float s = P[i];
    for (int j = 1; j < nsplit; ++j) s += P[i + (size_t)j * (size_t)pstride];
    s += bias[i % N];
    if (relu) s = fmaxf(s, 0.f);
    H[i] = s;
}

// ---- combine split-K partials + bias + relu, emit pre-split bf16 hi/lo; float4 wide ----
__global__ void combine_bias_split(const float* __restrict__ P, const float* __restrict__ bias,
                                   unsigned short* __restrict__ Hhi, unsigned short* __restrict__ Hlo,
                                   int total, int N, int nsplit, int pstride, int relu)
{
    int i = (blockIdx.x * blockDim.x + threadIdx.x) * 4;
    if (i >= total) return;
    float4 s = *reinterpret_cast<const float4*>(P + i);
    for (int j = 1; j < nsplit; ++j) {
        float4 p = *reinterpret_cast<const float4*>(P + i + (size_t)j * (size_t)pstride);
        s.x += p.x; s.y += p.y; s.z += p.z; s.w += p.w;
    }
    const float4 b = *reinterpret_cast<const float4*>(bias + (i % N));
    s.x += b.x; s.y += b.y; s.z += b.z; s.w += b.w;
    if (relu) {
        s.x = fmaxf(s.x, 0.f); s.y = fmaxf(s.y, 0.f);
        s.z = fmaxf(s.z, 0.f); s.w = fmaxf(s.w, 0.f);
    }
    u16x4 hi = { f2bf_trunc(s.x), f2bf_trunc(s.y), f2bf_trunc(s.z), f2bf_trunc(s.w) };
    u16x4 lo = { f2bf_rne(s.x - bfhi_f32(s.x)), f2bf_rne(s.y - bfhi_f32(s.y)),
                 f2bf_rne(s.z - bfhi_f32(s.z)), f2bf_rne(s.w - bfhi_f32(s.w)) };
    *reinterpret_cast<u16x4*>(&Hhi[i]) = hi;
    *reinterpret_cast<u16x4*>(&Hlo[i]) = lo;
}

// combine for fused heads: dual bias (bc for col<91, br after); float4 wide
__global__ void combine_head(const float* __restrict__ P, const float* __restrict__ bc,
                             const float* __restrict__ br, float* __restrict__ H,
                             int total, int nsplit, int pstride)
{
    int i = (blockIdx.x * blockDim.x + threadIdx.x) * 4;
    if (i >= total) return;
    float4 s = *reinterpret_cast<const float4*>(P + i);
    for (int j = 1; j < nsplit; ++j) {
        float4 p = *reinterpret_cast<const float4*>(P + i + (size_t)j * (size_t)pstride);
        s.x += p.x; s.y += p.y; s.z += p.z; s.w += p.w;
    }
    float sv[4] = {s.x, s.y, s.z, s.w};
#pragma unroll
    for (int e = 0; e < 4; ++e) {
        int col = (i + e) % 455;
        sv[e] += (col < 91) ? bc[col] : br[col - 91];
    }
    *reinterpret_cast<float4*>(&H[i]) = make_float4(sv[0], sv[1], sv[2], sv[3]);
}

__device__ __forceinline__ float scalar_dim(const int* p)
{
    int iv = *p;
    return (iv > 0 && iv < (1 << 20)) ? (float)iv : *reinterpret_cast<const float*>(p);
}

// ---------------- decode + softmax + threshold + per-class bucket compact ----------------
__global__ __launch_bounds__(128) void decode_compact(
    const float* __restrict__ logits, int lstr, const float* __restrict__ breg, int bstr,
    const float4* __restrict__ proposals, const int* __restrict__ ihp,
    const int* __restrict__ iwp,
    float4* __restrict__ cbox, float* __restrict__ cscore, int* __restrict__ cn,
    int* __restrict__ ccnt)
{
    const int n = blockIdx.x;
    const int c = threadIdx.x;
    __shared__ float sl[91];
    __shared__ float red[128];
    if (c < 91) sl[c] = logits[(size_t)n * lstr + c];
    __syncthreads();
    red[c] = (c < 91) ? sl[c] : -3.0e38f;
    __syncthreads();
#pragma unroll
    for (int s = 64; s > 0; s >>= 1) {
        if (c < s) red[c] = fmaxf(red[c], red[c + s]);
        __syncthreads();
    }
    const float s_max = red[0];
    __syncthreads();
    red[c] = (c < 91) ? expf(sl[c] - s_max) : 0.f;
    __syncthreads();
#pragma unroll
    for (int s = 64; s > 0; s >>= 1) {
        if (c < s) red[c] += red[c + s];
        __syncthreads();
    }
    const float s_sum = red[0];
    if (c < 1 || c >= 91) return;

    const float score = expf(sl[c] - s_max) / s_sum;
    const float Wim = scalar_dim(iwp), Him = scalar_dim(ihp);
    float4 p = proposals[n];
    float pw = p.z - p.x, ph = p.w - p.y;
    float pcx = p.x + 0.5f * pw, pcy = p.y + 0.5f * ph;
    const float* r4 = breg + (size_t)n * bstr + c * 4;
    float dxv = r4[0] / 10.f, dyv = r4[1] / 10.f;
    const float BCLIP = 4.135166556742356f;
    float dwv = fminf(r4[2] / 5.f, BCLIP);
    float dhv = fminf(r4[3] / 5.f, BCLIP);
    float cx = dxv * pw + pcx, cy = dyv * ph + pcy;
    float w = expf(dwv) * pw, hh = expf(dhv) * ph;
    float x1 = cx - 0.5f * w, y1 = cy - 0.5f * hh;
    float x2 = cx + 0.5f * w, y2 = cy + 0.5f * hh;
    x1 = fminf(fmaxf(x1, 0.f), Wim);
    y1 = fminf(fmaxf(y1, 0.f), Him);
    x2 = fminf(fmaxf(x2, 0.f), Wim);
    y2 = fminf(fmaxf(y2, 0.f), Him);
    float bw = x2 - x1, bh = y2 - y1;
    if (score > 0.05f && bw >= 0.01f && bh >= 0.01f) {
        int cls = c - 1;
        int pos = atomicAdd(&ccnt[cls], 1);
        if (pos < CPC) {
            cbox[cls * CPC + pos] = make_float4(x1, y1, x2, y2);
            cscore[cls * CPC + pos] = score;
            cn[cls * CPC + pos] = n;
        }
    }
}

// ---------------- per-class greedy NMS ----------------
__global__ __launch_bounds__(256) void nms_class(
    const float4* __restrict__ cbox, const float* __restrict__ cscore,
    const int* __restrict__ cn, const int* __restrict__ ccnt,
    float4* __restrict__ sbox, float* __restrict__ sscore,
    unsigned long long* __restrict__ skey, int* __restrict__ scnt)
{
    const int cls = blockIdx.x;
    const int tid = threadIdx.x;
    int cnt = ccnt[cls]; if (cnt > CPC) cnt = CPC;

    __shared__ float4 cb[CPC];
    __shared__ unsigned long long keys[CPC];
    __shared__ unsigned long long red[4];
    __shared__ float4 selsh;
    __shared__ int selidx_sh;

    for (int i = tid; i < cnt; i += 256) {
        cb[i] = cbox[cls * CPC + i];
        unsigned int sb = __float_as_uint(cscore[cls * CPC + i]);
        sb ^= (sb >> 31) ? 0xFFFFFFFFu : 0x80000000u;
        unsigned int flat = (unsigned)cn[cls * CPC + i] * 90u + (unsigned)cls;
        keys[i] = ((unsigned long long)sb << 32) | (unsigned long long)(0xFFFFFFFFu - flat);
    }
    __syncthreads();

    int sel = 0;
    while (sel < SPC) {
        unsigned long long best = 0ull;
        for (int i = tid; i < cnt; i += 256) {
            unsigned long long k = keys[i];
            if (k > best) best = k;
        }
#pragma unroll
        for (int d = 32; d >= 1; d >>= 1) {
            unsigned long long o = __shfl_down(best, d, 64);
            if (o > best) best = o;
        }
        if ((tid & 63) == 0) red[tid >> 6] = best;
        __syncthreads();
        unsigned long long gbest = red[0];
        if (red[1] > gbest) gbest = red[1];
        if (red[2] > gbest) gbest = red[2];
        if (red[3] > gbest) gbest = red[3];
        if (gbest == 0ull) break;
        for (int i = tid; i < cnt; i += 256)
            if (keys[i] == gbest) { selsh = cb[i]; selidx_sh = i; }
        __syncthreads();
        float4 s = selsh;
        const int si = selidx_sh;
        const float sa = (s.z - s.x) * (s.w - s.y);
        if (tid == 0) {
            sbox[cls * SPC + sel] = s;
            unsigned int sb = (unsigned int)(gbest >> 32);
            sb ^= (sb >> 31) ? 0x80000000u : 0xFFFFFFFFu;
            sscore[cls * SPC + sel] = __uint_as_float(sb);
            skey[cls * SPC + sel] = gbest;
        }
        for (int i = tid; i < cnt; i += 256) {
            float4 b = cb[i];
            float xx1 = fmaxf(s.x, b.x), yy1 = fmaxf(s.y, b.y);
            float xx2 = fminf(s.z, b.z), yy2 = fminf(s.w, b.w);
            float inter = fmaxf(xx2 - xx1, 0.f) * fmaxf(yy2 - yy1, 0.f);
            float area = (b.z - b.x) * (b.w - b.y);
            if (3.f * inter > sa + area + 1e-9f || i == si) keys[i] = 0ull;
        }
        ++sel;
        __syncthreads();
    }
    if (tid == 0) scnt[cls] = sel;
}

// ---------------- 90-way merge ----------------
__global__ __launch_bounds__(128) void nms_merge(
    const float4* __restrict__ sbox, const float* __restrict__ sscore,
    const unsigned long long* __restrict__ skey, const int* __restrict__ scnt,
    float* __restrict__ out)
{
    const int tid = threadIdx.x;
    __shared__ int head[NCLS];
    __shared__ unsigned long long red[2];
    __shared__ int selc_sh;
    if (tid < NCLS) head[tid] = 0;
    __syncthreads();

    for (int k = 0; k < 100; ++k) {
        unsigned long long key = 0ull;
        if (tid < NCLS && head[tid] < scnt[tid]) key = skey[tid * SPC + head[tid]];
        unsigned long long mykey = key;
#pragma unroll
        for (int d = 32; d >= 1; d >>= 1) {
            unsigned long long o = __shfl_down(key, d, 64);
            if (o > key) key = o;
        }
        if ((tid & 63) == 0) red[tid >> 6] = key;
        if (tid == 0) selc_sh = -1;
        __syncthreads();
        unsigned long long gbest = red[0] > red[1] ? red[0] : red[1];
        if (gbest != 0ull && mykey == gbest) selc_sh = tid;
        __syncthreads();
        const int c = selc_sh;
        if (tid == 0) {
            if (c >= 0) {
                int h = head[c];
                float4 b = sbox[c * SPC + h];
                out[k * 4 + 0] = b.x; out[k * 4 + 1] = b.y;
                out[k * 4 + 2] = b.z; out[k * 4 + 3] = b.w;
                out[400 + k] = sscore[c * SPC + h];
                out[500 + k] = (float)(c + 1);
            } else {
                out[k * 4 + 0] = 0.f; out[k * 4 + 1] = 0.f;
                out[k * 4 + 2] = 0.f; out[k * 4 + 3] = 0.f;
                out[400 + k] = 0.f; out[500 + k] = 0.f;
            }
        }
        if (c >= 0 && tid == c) head[c]++;
        __syncthreads();
    }
}

// ------------------------------------------------------------------------
extern "C" void kernel_launch(void* const* d_in, const int* in_sizes, int n_in,
                              void* d_out, int out_size, void* d_ws, size_t ws_size,
                              hipStream_t stream)
{
    const float* bf    = (const float*)d_in[0];
    const float* props = (const float*)d_in[1];
    const float* W1    = (const float*)d_in[2];
    const float* b1    = (const float*)d_in[3];
    const float* W2    = (const float*)d_in[4];
    const float* b2    = (const float*)d_in[5];
    const float* Wc    = (const float*)d_in[6];
    const float* bc    = (const float*)d_in[7];
    const float* Wr    = (const float*)d_in[8];
    const float* br    = (const float*)d_in[9];
    const int*   ihp   = (const int*)d_in[10];
    const int*   iwp   = (const int*)d_in[11];
    float* ws  = (float*)d_ws;
    float* out = (float*)d_out;

    const size_t MN   = 2000ull * 1024ull;      // 2,048,000
    const size_t NLOG = 2000ull * 91ull;
    const size_t NREG = 2000ull * 364ull;
    const size_t NHEAD = 2000ull * 455ull;      // 910,000
    const size_t ws_floats = ws_size / 4;

    // ---- MFMA-path layout (float units); NEED formula unchanged ----
    const size_t BT1F = 1024ull * 12544ull / 2;   // 6,422,528 per bf16 array
    const size_t WT2F = 1024ull * 1024ull / 2;    // 524,288
    const size_t WHF  = 455ull * 1024ull / 2;     // 232,960
    const size_t NMSF = (size_t)NCLS * CPC * 6 + (size_t)NCLS * SPC * 7 + 256;
    const size_t PF   = 4 * MN;                   // 8,192,000 (covers 8*NHEAD too)
    const size_t NEED = 2 * BT1F + 2 * WT2F + 2 * WHF + 2 * MN + NHEAD + NMSF + PF + 64;

    if (ws_floats >= NEED) {
        // ===== bf16x3 MFMA path: prefetch GEMMs @4/CU + XCD swizzle + fast tail =====
        unsigned short* BT1hi = (unsigned short*)ws;
        unsigned short* BT1lo = (unsigned short*)(ws + BT1F);
        unsigned short* WT2hi = (unsigned short*)(ws + 2 * BT1F);
        unsigned short* WT2lo = (unsigned short*)(ws + 2 * BT1F + WT2F);
        unsigned short* WHhi  = (unsigned short*)(ws + 2 * BT1F + 2 * WT2F);
        unsigned short* WHlo  = (unsigned short*)(ws + 2 * BT1F + 2 * WT2F + WHF);
        float* H1   = ws + 2 * BT1F + 2 * WT2F + 2 * WHF;
        float* H2   = H1 + MN;
        float* HEAD = H2 + MN;
        float* CBOX   = HEAD + NHEAD;
        float* CSCORE = CBOX + (size_t)NCLS * CPC * 4;
        int*   CN     = (int*)(CSCORE + (size_t)NCLS * CPC);
        float* SBOX   = (float*)(CN + (size_t)NCLS * CPC);
        float* SSCORE = SBOX + (size_t)NCLS * SPC * 4;
        unsigned long long* SKEY = (unsigned long long*)(SSCORE + (size_t)NCLS * SPC);
        int*   CCNT = (int*)(SKEY + (size_t)NCLS * SPC);
        int*   SCNT = CCNT + NCLS;
        float* P = (float*)(SCNT + NCLS + 64);    // +64 pad: 16B-align P for float4 combines

        unsigned short* H1hi = (unsigned short*)H1;
        unsigned short* H1lo = H1hi + MN;
        unsigned short* H2hi = (unsigned short*)H2;
        unsigned short* H2lo = H2hi + MN;

        // 0) weight splits (64k x 32n tiles, short2 stores)
        split_transpose<<<dim3(196, 32), 256, 0, stream>>>(W1, BT1hi, BT1lo, 12544, 1024);
        split_transpose<<<dim3(16, 32), 256, 0, stream>>>(W2, WT2hi, WT2lo, 1024, 1024);
        split_transpose2<<<dim3(16, 15), 256, 0, stream>>>(Wc, Wr, 91, 364, WHhi, WHlo, 1024);
        // 1) GEMM1: 2000x12544x1024, z=4, 1024 blocks (4/CU)
        gemm_bf16x3_f32a<<<dim3(8, 32, 4), 256, 0, stream>>>(bf, BT1hi, BT1lo, P,
                                                             2000, 1024, 12544, 3136);
        combine_bias_split<<<(int)(MN / 4 / 256), 256, 0, stream>>>(P, b1, H1hi, H1lo,
                                                             (int)MN, 1024, 4, (int)MN, 1);
        // 2) GEMM2: 2000x1024x1024, z=4
        gemm_bf16x3_sa<<<dim3(8, 32, 4), 256, 0, stream>>>(H1hi, H1lo, WT2hi, WT2lo, P,
                                                           2000, 1024, 1024, 256);
        combine_bias_split<<<(int)(MN / 4 / 256), 256, 0, stream>>>(P, b2, H2hi, H2lo,
                                                             (int)MN, 1024, 4, (int)MN, 1);
        // 3) fused heads: 2000x1024x455, z=8
        gemm_bf16x3_sa<<<dim3(4, 32, 8), 256, 0, stream>>>(H2hi, H2lo, WHhi, WHlo, P,
                                                           2000, 455, 1024, 128);
        combine_head<<<(int)((NHEAD / 4 + 255) / 256), 256, 0, stream>>>(P, bc, br, HEAD,
                                                             (int)NHEAD, 8, (int)NHEAD);
        // 4) decode + compaction; 5) per-class NMS; 6) merge
        hipMemsetAsync(CCNT, 0, 2 * NCLS * sizeof(int), stream);
        decode_compact<<<2000, 128, 0, stream>>>(HEAD, 455, HEAD + 91, 455,
                                                 (const float4*)props, ihp, iwp,
                                                 (float4*)CBOX, CSCORE, CN, CCNT);
        nms_class<<<NCLS, 256, 0, stream>>>((const float4*)CBOX, CSCORE, CN, CCNT,
                                            (float4*)SBOX, SSCORE, SKEY, SCNT);
        nms_merge<<<1, 128, 0, stream>>>((const float4*)SBOX, SSCORE, SKEY, SCNT, out);
        return;
    }

    // ================= fallback: fp32 vector path =================
    const size_t NMSF2 = (size_t)NCLS * CPC * 6 + (size_t)NCLS * SPC * 7 + 256;
    const size_t TAILF = 2 * MN + NLOG + NREG + NMSF2;
    int z1 = 2;
    if (ws_floats >= TAILF + 8 * MN) z1 = 8;
    else if (ws_floats >= TAILF + 4 * MN) z1 = 4;
    const size_t REUSE = (size_t)z1 * MN;
    int zh = (REUSE >= 8 * NREG) ? 8 : 4;

    float* P      = ws;
    float* H1     = P + REUSE;
    float* H2     = H1 + MN;
    float* LOG    = H2 + MN;
    float* BREG   = LOG + NLOG;
    float* CBOX   = BREG + NREG;
    float* CSCORE = CBOX + (size_t)NCLS * CPC * 4;
    int*   CN     = (int*)(CSCORE + (size_t)NCLS * CPC);
    float* SBOX   = (float*)(CN + (size_t)NCLS * CPC);
    float* SSCORE = SBOX + (size_t)NCLS * SPC * 4;
    unsigned long long* SKEY = (unsigned long long*)(SSCORE + (size_t)NCLS * SPC);
    int*   CCNT   = (int*)(SKEY + (size_t)NCLS * SPC);
    int*   SCNT   = CCNT + NCLS;

    gemm_f32<<<dim3(8, 16, z1), 256, 0, stream>>>(bf, W1, nullptr, P,
                                                  2000, 1024, 12544, 12544 / z1, 0);
    combine_bias_act<<<(int)((MN + 255) / 256), 256, 0, stream>>>(P, b1, H1,
                                                  (int)MN, 1024, z1, (int)MN, 1);
    gemm_f32<<<dim3(8, 16, 4), 256, 0, stream>>>(H1, W2, nullptr, P,
                                                 2000, 1024, 1024, 256, 0);
    combine_bias_act<<<(int)((MN + 255) / 256), 256, 0, stream>>>(P, b2, H2,
                                                 (int)MN, 1024, 4, (int)MN, 1);
    gemm_f32<<<dim3(1, 16, zh), 256, 0, stream>>>(H2, Wc, nullptr, P,
                                                  2000, 91, 1024, 1024 / zh, 0);
    combine_bias_act<<<(int)((NLOG + 255) / 256), 256, 0, stream>>>(P, bc, LOG,
                                                  (int)NLOG, 91, zh, (int)NLOG, 0);
    gemm_f32<<<dim3(3, 16, zh), 256, 0, stream>>>(H2, Wr, nullptr, P,
                                                  2000, 364, 1024, 1024 / zh, 0);
    combine_bias_act<<<(int)((NREG + 255) / 256), 256, 0, stream>>>(P, br, BREG,
                                                  (int)NREG, 364, zh, (int)NREG, 0);
    hipMemsetAsync(CCNT, 0, 2 * NCLS * sizeof(int), stream);
    decode_compact<<<2000, 128, 0, stream>>>(LOG, 91, BREG, 364,
                                             (const float4*)props, ihp, iwp,
                                             (float4*)CBOX, CSCORE, CN, CCNT);
    nms_class<<<NCLS, 256, 0, stream>>>((const float4*)CBOX, CSCORE, CN, CCNT,
                                        (float4*)SBOX, SSCORE, SKEY, SCNT);
    nms_merge<<<1, 128, 0, stream>>>((const float4*)SBOX, SSCORE, SKEY, SCNT, out);
}

// Round 8
// 724.509 us; speedup vs baseline: 1.0291x; 1.0291x over previous
//
#include <hip/hip_runtime.h>

#define CPC 2000          // max candidates per class
#define SPC 100           // max survivors per class
#define NCLS 90
#define TM 128
#define TN 128
#define TKK 16

typedef __attribute__((ext_vector_type(8))) short bf16x8;
typedef __attribute__((ext_vector_type(4))) float f32x4;
typedef __attribute__((ext_vector_type(4))) unsigned short u16x4;

// ---------------- helpers ----------------
__device__ __forceinline__ unsigned short f2bf_rne(float f) {
    unsigned u = __float_as_uint(f);
    return (unsigned short)((u + 0x7FFFu + ((u >> 16) & 1u)) >> 16);
}
__device__ __forceinline__ unsigned short f2bf_trunc(float f) {
    return (unsigned short)(__float_as_uint(f) >> 16);
}
__device__ __forceinline__ float bfhi_f32(float f) {
    return __uint_as_float(__float_as_uint(f) & 0xFFFF0000u);
}
__device__ __forceinline__ void async_load16(const void* g, void* l) {
    __builtin_amdgcn_global_load_lds((const __attribute__((address_space(1))) unsigned int*)g,
                                     (__attribute__((address_space(3))) unsigned int*)l, 16, 0, 0);
}
// XOR swizzle on 16B-chunk index (involution; same on write/source and read)
__device__ __forceinline__ int swz(int c) { return c ^ ((c >> 3) & 3); }

// XCD-aware block remap (T1): bijective when nwg%8==0; contiguous chunk per XCD.
__device__ __forceinline__ void xcd_remap(unsigned& bx, unsigned& by, unsigned& bz)
{
    const unsigned nx = gridDim.x, ny = gridDim.y;
    const unsigned nwg = nx * ny * gridDim.z;
    unsigned lin = blockIdx.x + nx * (blockIdx.y + ny * blockIdx.z);
    if ((nwg & 7u) == 0u)
        lin = (lin & 7u) * (nwg >> 3) + (lin >> 3);
    bx = lin % nx;
    unsigned rem = lin / nx;
    by = rem % ny;
    bz = rem / ny;
}

// ---------------- merged weight prep: all 3 split-transposes + CCNT zero -------------
// Per-tile math identical to prior split_transpose/split_transpose2 (64k x 32n tiles,
// packed short2 stores).  One launch instead of 3 kernels + 1 memset.
__device__ __forceinline__ void st_tile(
    const float* __restrict__ W, unsigned short* __restrict__ Thi,
    unsigned short* __restrict__ Tlo, int K, int N, int bx, int by)
{
    __shared__ float tile[64][33];
    const int kt = bx * 64, nt = by * 32;
    const int tx = threadIdx.x & 31, ty = threadIdx.x >> 5;
#pragma unroll
    for (int j = 0; j < 8; ++j) {
        int k = kt + ty + j * 8, n = nt + tx;
        tile[ty + j * 8][tx] = (k < K && n < N) ? W[(size_t)k * N + n] : 0.f;
    }
    __syncthreads();
#pragma unroll
    for (int j = 0; j < 4; ++j) {
        int n = nt + ty + j * 8;
        int k = kt + tx * 2;
        if (n < N && k < K) {
            float f0 = tile[tx * 2][ty + j * 8];
            float f1 = tile[tx * 2 + 1][ty + j * 8];
            unsigned hi = (unsigned)f2bf_trunc(f0) | ((unsigned)f2bf_trunc(f1) << 16);
            unsigned lo = (unsigned)f2bf_rne(f0 - bfhi_f32(f0))
                        | ((unsigned)f2bf_rne(f1 - bfhi_f32(f1)) << 16);
            *reinterpret_cast<unsigned*>(&Thi[(size_t)n * K + k]) = hi;
            *reinterpret_cast<unsigned*>(&Tlo[(size_t)n * K + k]) = lo;
        }
    }
}

__device__ __forceinline__ void st_tile2(
    const float* __restrict__ Wa, const float* __restrict__ Wb, int Na, int Nb,
    unsigned short* __restrict__ Thi, unsigned short* __restrict__ Tlo, int K,
    int bx, int by)
{
    const int N = Na + Nb;
    __shared__ float tile[64][33];
    const int kt = bx * 64, nt = by * 32;
    const int tx = threadIdx.x & 31, ty = threadIdx.x >> 5;
#pragma unroll
    for (int j = 0; j < 8; ++j) {
        int k = kt + ty + j * 8, n = nt + tx;
        float v = 0.f;
        if (k < K && n < N)
            v = (n < Na) ? Wa[(size_t)k * Na + n] : Wb[(size_t)k * Nb + (n - Na)];
        tile[ty + j * 8][tx] = v;
    }
    __syncthreads();
#pragma unroll
    for (int j = 0; j < 4; ++j) {
        int n = nt + ty + j * 8;
        int k = kt + tx * 2;
        if (n < N && k < K) {
            float f0 = tile[tx * 2][ty + j * 8];
            float f1 = tile[tx * 2 + 1][ty + j * 8];
            unsigned hi = (unsigned)f2bf_trunc(f0) | ((unsigned)f2bf_trunc(f1) << 16);
            unsigned lo = (unsigned)f2bf_rne(f0 - bfhi_f32(f0))
                        | ((unsigned)f2bf_rne(f1 - bfhi_f32(f1)) << 16);
            *reinterpret_cast<unsigned*>(&Thi[(size_t)n * K + k]) = hi;
            *reinterpret_cast<unsigned*>(&Tlo[(size_t)n * K + k]) = lo;
        }
    }
}

// sections: [0, 6272) W1 (196x32) | [6272, 6784) W2 (16x32) | [6784, 7024) WcWr (16x15)
// block 7024: zero CCNT/SCNT (2*NCLS ints)
__global__ __launch_bounds__(256) void prep_weights(
    const float* __restrict__ W1, unsigned short* __restrict__ T1hi, unsigned short* __restrict__ T1lo,
    const float* __restrict__ W2, unsigned short* __restrict__ T2hi, unsigned short* __restrict__ T2lo,
    const float* __restrict__ Wc, const float* __restrict__ Wr,
    unsigned short* __restrict__ THhi, unsigned short* __restrict__ THlo,
    int* __restrict__ ccnt)
{
    const int b = blockIdx.x;
    if (b < 6272) {
        st_tile(W1, T1hi, T1lo, 12544, 1024, b % 196, b / 196);
    } else if (b < 6784) {
        int lb = b - 6272;
        st_tile(W2, T2hi, T2lo, 1024, 1024, lb % 16, lb / 16);
    } else if (b < 7024) {
        int lb = b - 6784;
        st_tile2(Wc, Wr, 91, 364, THhi, THlo, 1024, lb % 16, lb / 16);
    } else {
        if (threadIdx.x < 2 * NCLS) ccnt[threadIdx.x] = 0;
    }
}

// ---------------- bf16x3 MFMA GEMM, 64x128 tile, fp32 A split on the fly --------------
// C = Ahi*Bhi + Alo*Bhi + Ahi*Blo.  R5-proven config: single-buffer, 2 barriers/step,
// launch_bounds(256,4) (VGPR 48), 24 KB LDS, + T1 XCD swizzle.
__global__ __launch_bounds__(256, 4) void gemm_bf16x3_f32a(
    const float* __restrict__ A, const unsigned short* __restrict__ Bhi,
    const unsigned short* __restrict__ Blo, float* __restrict__ C,
    int M, int N, int K, int klen)      // klen multiple of 32
{
    __shared__ unsigned short Ah[2048], Al[2048], Bh[4096], Bl[4096];  // 24 KB
    unsigned bxu, byu, bzu;
    xcd_remap(bxu, byu, bzu);
    const int tid = threadIdx.x;
    const int wv = tid >> 6, ln = tid & 63;
    const int q = ln >> 4, lm = ln & 15;
    const int m0 = byu * 64, n0 = bxu * 128;
    const int k0 = bzu * klen;
    int k1 = k0 + klen; if (k1 > K) k1 = K;
    const int bcol_t = wv * 32;

    f32x4 acc[4][2];
#pragma unroll
    for (int i = 0; i < 4; ++i)
#pragma unroll
        for (int j = 0; j < 2; ++j) acc[i][j] = (f32x4)0.f;

    // A staging: thread t loads row r=t>>2, k-octet h=t&3 (8 fp32 = 32B, quad = 128B)
    int gr = m0 + (tid >> 2); if (gr >= M) gr = M - 1;     // clamp: dup read, never stored
    const float* Arow = A + (size_t)gr * K + (tid & 3) * 8;
    const int apc = swz(tid);                              // physical chunk for A write

    // B staging: slot s holds logical chunk swz(s): col = s>>2, octet = (s&3)^((s>>3)&3)
    unsigned bsrc[2];
#pragma unroll
    for (int i = 0; i < 2; ++i) {
        int s = i * 256 + tid;
        int gn = n0 + (s >> 2); if (gn >= N) gn = N - 1;   // clamp (dup read, unstored)
        int qe = (s & 3) ^ ((s >> 3) & 3);
        bsrc[i] = (unsigned)gn * (unsigned)K + (unsigned)(qe * 8);
    }

    for (int kt = k0; kt < k1; kt += 32) {
        // ---- B tiles (hi & lo): 4 x global_load_lds 16B per thread, quad-coalesced
#pragma unroll
        for (int i = 0; i < 2; ++i) {
            async_load16(Bhi + bsrc[i] + kt, &Bh[(i * 256 + wv * 64) * 8]);
            async_load16(Blo + bsrc[i] + kt, &Bl[(i * 256 + wv * 64) * 8]);
        }
        // ---- A: 8 fp32, split hi/lo, one chunk per array
        float4 v0 = *reinterpret_cast<const float4*>(Arow + kt);
        float4 v1 = *reinterpret_cast<const float4*>(Arow + kt + 4);
        float f[8] = {v0.x, v0.y, v0.z, v0.w, v1.x, v1.y, v1.z, v1.w};
        bf16x8 hi, lo;
#pragma unroll
        for (int e = 0; e < 8; ++e) {
            hi[e] = (short)f2bf_trunc(f[e]);
            lo[e] = (short)f2bf_rne(f[e] - bfhi_f32(f[e]));
        }
        *(bf16x8*)&Ah[apc * 8] = hi;
        *(bf16x8*)&Al[apc * 8] = lo;
        __syncthreads();

        // ---- fragments
        bf16x8 afh[4], afl[4], bfh[2], bfl[2];
#pragma unroll
        for (int mi = 0; mi < 4; ++mi) {
            int p = swz((mi * 16 + lm) * 4 + q);
            afh[mi] = *(const bf16x8*)&Ah[p * 8];
            afl[mi] = *(const bf16x8*)&Al[p * 8];
        }
#pragma unroll
        for (int ni = 0; ni < 2; ++ni) {
            int p = swz((bcol_t + ni * 16 + lm) * 4 + q);
            bfh[ni] = *(const bf16x8*)&Bh[p * 8];
            bfl[ni] = *(const bf16x8*)&Bl[p * 8];
        }
#pragma unroll
        for (int mi = 0; mi < 4; ++mi)
#pragma unroll
            for (int ni = 0; ni < 2; ++ni) {
                acc[mi][ni] = __builtin_amdgcn_mfma_f32_16x16x32_bf16(afh[mi], bfh[ni], acc[mi][ni], 0, 0, 0);
                acc[mi][ni] = __builtin_amdgcn_mfma_f32_16x16x32_bf16(afl[mi], bfh[ni], acc[mi][ni], 0, 0, 0);
                acc[mi][ni] = __builtin_amdgcn_mfma_f32_16x16x32_bf16(afh[mi], bfl[ni], acc[mi][ni], 0, 0, 0);
            }
        __syncthreads();
    }

    // ---- store partials: C/D layout row=q*4+ri, col=lm
    float* Cz = C + (size_t)bzu * (size_t)M * (size_t)N;
#pragma unroll
    for (int mi = 0; mi < 4; ++mi)
#pragma unroll
        for (int ni = 0; ni < 2; ++ni)
#pragma unroll
            for (int ri = 0; ri < 4; ++ri) {
                int rr = m0 + mi * 16 + q * 4 + ri;
                int cc = n0 + bcol_t + ni * 16 + lm;
                if (rr < M && cc < N) Cz[(size_t)rr * N + cc] = acc[mi][ni][ri];
            }
}

// ---------------- bf16x3 MFMA GEMM, 64x128 tile, pre-split A (pure global_load_lds) ----
__global__ __launch_bounds__(256, 4) void gemm_bf16x3_sa(
    const unsigned short* __restrict__ Ahi_g, const unsigned short* __restrict__ Alo_g,
    const unsigned short* __restrict__ Bhi, const unsigned short* __restrict__ Blo,
    float* __restrict__ C, int M, int N, int K, int klen)
{
    __shared__ unsigned short Ah[2048], Al[2048], Bh[4096], Bl[4096];
    unsigned bxu, byu, bzu;
    xcd_remap(bxu, byu, bzu);
    const int tid = threadIdx.x;
    const int wv = tid >> 6, ln = tid & 63;
    const int q = ln >> 4, lm = ln & 15;
    const int m0 = byu * 64, n0 = bxu * 128;
    const int k0 = bzu * klen;
    int k1 = k0 + klen; if (k1 > K) k1 = K;
    const int bcol_t = wv * 32;

    f32x4 acc[4][2];
#pragma unroll
    for (int i = 0; i < 4; ++i)
#pragma unroll
        for (int j = 0; j < 2; ++j) acc[i][j] = (f32x4)0.f;

    // A: physical slot tid holds logical chunk swz(tid) -> pre-XORed source octet
    int agr = m0 + (tid >> 2); if (agr >= M) agr = M - 1;
    const unsigned asrc = (unsigned)agr * (unsigned)K
                        + (unsigned)(((tid & 3) ^ ((tid >> 3) & 3)) * 8);

    unsigned bsrc[2];
#pragma unroll
    for (int i = 0; i < 2; ++i) {
        int s = i * 256 + tid;
        int gn = n0 + (s >> 2); if (gn >= N) gn = N - 1;
        int qe = (s & 3) ^ ((s >> 3) & 3);
        bsrc[i] = (unsigned)gn * (unsigned)K + (unsigned)(qe * 8);
    }

    for (int kt = k0; kt < k1; kt += 32) {
        async_load16(Ahi_g + asrc + kt, &Ah[(wv * 64) * 8]);
        async_load16(Alo_g + asrc + kt, &Al[(wv * 64) * 8]);
#pragma unroll
        for (int i = 0; i < 2; ++i) {
            async_load16(Bhi + bsrc[i] + kt, &Bh[(i * 256 + wv * 64) * 8]);
            async_load16(Blo + bsrc[i] + kt, &Bl[(i * 256 + wv * 64) * 8]);
        }
        __syncthreads();

        bf16x8 afh[4], afl[4], bfh[2], bfl[2];
#pragma unroll
        for (int mi = 0; mi < 4; ++mi) {
            int p = swz((mi * 16 + lm) * 4 + q);
            afh[mi] = *(const bf16x8*)&Ah[p * 8];
            afl[mi] = *(const bf16x8*)&Al[p * 8];
        }
#pragma unroll
        for (int ni = 0; ni < 2; ++ni) {
            int p = swz((bcol_t + ni * 16 + lm) * 4 + q);
            bfh[ni] = *(const bf16x8*)&Bh[p * 8];
            bfl[ni] = *(const bf16x8*)&Bl[p * 8];
        }
#pragma unroll
        for (int mi = 0; mi < 4; ++mi)
#pragma unroll
            for (int ni = 0; ni < 2; ++ni) {
                acc[mi][ni] = __builtin_amdgcn_mfma_f32_16x16x32_bf16(afh[mi], bfh[ni], acc[mi][ni], 0, 0, 0);
                acc[mi][ni] = __builtin_amdgcn_mfma_f32_16x16x32_bf16(afl[mi], bfh[ni], acc[mi][ni], 0, 0, 0);
                acc[mi][ni] = __builtin_amdgcn_mfma_f32_16x16x32_bf16(afh[mi], bfl[ni], acc[mi][ni], 0, 0, 0);
            }
        __syncthreads();
    }

    float* Cz = C + (size_t)bzu * (size_t)M * (size_t)N;
#pragma unroll
    for (int mi = 0; mi < 4; ++mi)
#pragma unroll
        for (int ni = 0; ni < 2; ++ni)
#pragma unroll
            for (int ri = 0; ri < 4; ++ri) {
                int rr = m0 + mi * 16 + q * 4 + ri;
                int cc = n0 + bcol_t + ni * 16 + lm;
                if (rr < M && cc < N) Cz[(size_t)rr * N + cc] = acc[mi][ni][ri];
            }
}

// ---------------- fp32 vector GEMM (fallback path only) ----------------
__global__ __launch_bounds__(256) void gemm_f32(
    const float* __restrict__ A, const float* __restrict__ B,
    const float* __restrict__ bias, float* __restrict__ C,
    int M, int N, int K, int ksplit, int relu)
{
    __shared__ float As[TKK][TM + 4];
    __shared__ float Bs[TKK][TN + 4];
    const int tid = threadIdx.x;
    const int tx = tid & 15, ty = tid >> 4;
    const int m0 = blockIdx.y * TM, n0 = blockIdx.x * TN;
    const int z = blockIdx.z;
    const int kstart = z * ksplit;
    const int kend = (kstart + ksplit < K) ? (kstart + ksplit) : K;
    float* Cz = C + (size_t)z * (size_t)M * (size_t)N;
    const bool nvec = ((N & 3) == 0);

    float acc[8][8];
#pragma unroll
    for (int i = 0; i < 8; ++i)
#pragma unroll
        for (int j = 0; j < 8; ++j) acc[i][j] = 0.f;

    for (int kt = kstart; kt < kend; kt += TKK) {
#pragma unroll
        for (int l = 0; l < 2; ++l) {
            int idx = tid + l * 256;
            int rr = idx >> 2, kq = idx & 3;
            float4 v = make_float4(0.f, 0.f, 0.f, 0.f);
            int grr = m0 + rr;
            if (grr < M)
                v = *reinterpret_cast<const float4*>(A + (size_t)grr * K + kt + (kq << 2));
            As[(kq << 2) + 0][rr] = v.x;
            As[(kq << 2) + 1][rr] = v.y;
            As[(kq << 2) + 2][rr] = v.z;
            As[(kq << 2) + 3][rr] = v.w;
        }
#pragma unroll
        for (int l = 0; l < 2; ++l) {
            int idx = tid + l * 256;
            int kk = idx >> 5, nq = idx & 31;
            int gn = n0 + (nq << 2);
            const float* bp = B + (size_t)(kt + kk) * N + gn;
            float4 v;
            if (nvec && gn + 3 < N) {
                v = *reinterpret_cast<const float4*>(bp);
            } else {
                v.x = (gn + 0 < N) ? bp[0] : 0.f;
                v.y = (gn + 1 < N) ? bp[1] : 0.f;
                v.z = (gn + 2 < N) ? bp[2] : 0.f;
                v.w = (gn + 3 < N) ? bp[3] : 0.f;
            }
            *reinterpret_cast<float4*>(&Bs[kk][nq << 2]) = v;
        }
        __syncthreads();
#pragma unroll
        for (int kk = 0; kk < TKK; ++kk) {
            float a[8], b[8];
            *reinterpret_cast<float4*>(&a[0]) = *reinterpret_cast<const float4*>(&As[kk][ty * 8]);
            *reinterpret_cast<float4*>(&a[4]) = *reinterpret_cast<const float4*>(&As[kk][ty * 8 + 4]);
            *reinterpret_cast<float4*>(&b[0]) = *reinterpret_cast<const float4*>(&Bs[kk][tx * 4]);
            *reinterpret_cast<float4*>(&b[4]) = *reinterpret_cast<const float4*>(&Bs[kk][64 + tx * 4]);
#pragma unroll
            for (int i = 0; i < 8; ++i)
#pragma unroll
                for (int j = 0; j < 8; ++j)
                    acc[i][j] = fmaf(a[i], b[j], acc[i][j]);
        }
        __syncthreads();
    }
#pragma unroll
    for (int i = 0; i < 8; ++i) {
        int grr = m0 + ty * 8 + i;
        if (grr >= M) continue;
#pragma unroll
        for (int j = 0; j < 8; ++j) {
            int gc = n0 + ((j < 4) ? (tx * 4 + j) : (64 + tx * 4 + (j - 4)));
            if (gc >= N) continue;
            float v = acc[i][j];
            if (bias) v += bias[gc];
            if (relu) v = fmaxf(v, 0.f);
            Cz[(size_t)grr * N + gc] = v;
        }
    }
}

// ---------------- combine split-K partials + bias (+relu), fp32 out (fallback) --------
__global__ void combine_bias_act(const float* __restrict__ P, const float* __restrict__ bias,
                                 float* __restrict__ H, int total, int N, int nsplit,
                                 int pstride, int relu)
{
    int i = blockIdx.x * blockDim.x + threadIdx.x;
    if (i >= total) return;
    float s = P[i];
    for (int j = 1; j < nsplit; ++j) s += P[i + (size_t)j * (size_t)pstride];
    s += bias[i % N];
    if (relu) s = fmaxf(s, 0.f);
    H[i] = s;
}

// ---- combine split-K partials + bias + relu, emit pre-split bf16 hi/lo; float4 wide ----
__global__ void combine_bias_split(const float* __restrict__ P, const float* __restrict__ bias,
                                   unsigned short* __restrict__ Hhi, unsigned short* __restrict__ Hlo,
                                   int total, int N, int nsplit, int pstride, int relu)
{
    int i = (blockIdx.x * blockDim.x + threadIdx.x) * 4;
    if (i >= total) return;
    float4 s = *reinterpret_cast<const float4*>(P + i);
    for (int j = 1; j < nsplit; ++j) {
        float4 p = *reinterpret_cast<const float4*>(P + i + (size_t)j * (size_t)pstride);
        s.x += p.x; s.y += p.y; s.z += p.z; s.w += p.w;
    }
    const float4 b = *reinterpret_cast<const float4*>(bias + (i % N));
    s.x += b.x; s.y += b.y; s.z += b.z; s.w += b.w;
    if (relu) {
        s.x = fmaxf(s.x, 0.f); s.y = fmaxf(s.y, 0.f);
        s.z = fmaxf(s.z, 0.f); s.w = fmaxf(s.w, 0.f);
    }
    u16x4 hi = { f2bf_trunc(s.x), f2bf_trunc(s.y), f2bf_trunc(s.z), f2bf_trunc(s.w) };
    u16x4 lo = { f2bf_rne(s.x - bfhi_f32(s.x)), f2bf_rne(s.y - bfhi_f32(s.y)),
                 f2bf_rne(s.z - bfhi_f32(s.z)), f2bf_rne(s.w - bfhi_f32(s.w)) };
    *reinterpret_cast<u16x4*>(&Hhi[i]) = hi;
    *reinterpret_cast<u16x4*>(&Hlo[i]) = lo;
}

// combine for fused heads: dual bias (bc for col<91, br after); float4 wide
__global__ void combine_head(const float* __restrict__ P, const float* __restrict__ bc,
                             const float* __restrict__ br, float* __restrict__ H,
                             int total, int nsplit, int pstride)
{
    int i = (blockIdx.x * blockDim.x + threadIdx.x) * 4;
    if (i >= total) return;
    float4 s = *reinterpret_cast<const float4*>(P + i);
    for (int j = 1; j < nsplit; ++j) {
        float4 p = *reinterpret_cast<const float4*>(P + i + (size_t)j * (size_t)pstride);
        s.x += p.x; s.y += p.y; s.z += p.z; s.w += p.w;
    }
    float sv[4] = {s.x, s.y, s.z, s.w};
#pragma unroll
    for (int e = 0; e < 4; ++e) {
        int col = (i + e) % 455;
        sv[e] += (col < 91) ? bc[col] : br[col - 91];
    }
    *reinterpret_cast<float4*>(&H[i]) = make_float4(sv[0], sv[1], sv[2], sv[3]);
}

__device__ __forceinline__ float scalar_dim(const int* p)
{
    int iv = *p;
    return (iv > 0 && iv < (1 << 20)) ? (float)iv : *reinterpret_cast<const float*>(p);
}

// ---------------- decode + softmax + threshold + per-class bucket compact ----------------
__global__ __launch_bounds__(128) void decode_compact(
    const float* __restrict__ logits, int lstr, const float* __restrict__ breg, int bstr,
    const float4* __restrict__ proposals, const int* __restrict__ ihp,
    const int* __restrict__ iwp,
    float4* __restrict__ cbox, float* __restrict__ cscore, int* __restrict__ cn,
    int* __restrict__ ccnt)
{
    const int n = blockIdx.x;
    const int c = threadIdx.x;
    __shared__ float sl[91];
    __shared__ float red[128];
    if (c < 91) sl[c] = logits[(size_t)n * lstr + c];
    __syncthreads();
    red[c] = (c < 91) ? sl[c] : -3.0e38f;
    __syncthreads();
#pragma unroll
    for (int s = 64; s > 0; s >>= 1) {
        if (c < s) red[c] = fmaxf(red[c], red[c + s]);
        __syncthreads();
    }
    const float s_max = red[0];
    __syncthreads();
    red[c] = (c < 91) ? expf(sl[c] - s_max) : 0.f;
    __syncthreads();
#pragma unroll
    for (int s = 64; s > 0; s >>= 1) {
        if (c < s) red[c] += red[c + s];
        __syncthreads();
    }
    const float s_sum = red[0];
    if (c < 1 || c >= 91) return;

    const float score = expf(sl[c] - s_max) / s_sum;
    const float Wim = scalar_dim(iwp), Him = scalar_dim(ihp);
    float4 p = proposals[n];
    float pw = p.z - p.x, ph = p.w - p.y;
    float pcx = p.x + 0.5f * pw, pcy = p.y + 0.5f * ph;
    const float* r4 = breg + (size_t)n * bstr + c * 4;
    float dxv = r4[0] / 10.f, dyv = r4[1] / 10.f;
    const float BCLIP = 4.135166556742356f;
    float dwv = fminf(r4[2] / 5.f, BCLIP);
    float dhv = fminf(r4[3] / 5.f, BCLIP);
    float cx = dxv * pw + pcx, cy = dyv * ph + pcy;
    float w = expf(dwv) * pw, hh = expf(dhv) * ph;
    float x1 = cx - 0.5f * w, y1 = cy - 0.5f * hh;
    float x2 = cx + 0.5f * w, y2 = cy + 0.5f * hh;
    x1 = fminf(fmaxf(x1, 0.f), Wim);
    y1 = fminf(fmaxf(y1, 0.f), Him);
    x2 = fminf(fmaxf(x2, 0.f), Wim);
    y2 = fminf(fmaxf(y2, 0.f), Him);
    float bw = x2 - x1, bh = y2 - y1;
    if (score > 0.05f && bw >= 0.01f && bh >= 0.01f) {
        int cls = c - 1;
        int pos = atomicAdd(&ccnt[cls], 1);
        if (pos < CPC) {
            cbox[cls * CPC + pos] = make_float4(x1, y1, x2, y2);
            cscore[cls * CPC + pos] = score;
            cn[cls * CPC + pos] = n;
        }
    }
}

// ---------------- per-class greedy NMS ----------------
__global__ __launch_bounds__(256) void nms_class(
    const float4* __restrict__ cbox, const float* __restrict__ cscore,
    const int* __restrict__ cn, const int* __restrict__ ccnt,
    float4* __restrict__ sbox, float* __restrict__ sscore,
    unsigned long long* __restrict__ skey, int* __restrict__ scnt)
{
    const int cls = blockIdx.x;
    const int tid = threadIdx.x;
    int cnt = ccnt[cls]; if (cnt > CPC) cnt = CPC;

    __shared__ float4 cb[CPC];
    __shared__ unsigned long long keys[CPC];
    __shared__ unsigned long long red[4];
    __shared__ float4 selsh;
    __shared__ int selidx_sh;

    for (int i = tid; i < cnt; i += 256) {
        cb[i] = cbox[cls * CPC + i];
        unsigned int sb = __float_as_uint(cscore[cls * CPC + i]);
        sb ^= (sb >> 31) ? 0xFFFFFFFFu : 0x80000000u;
        unsigned int flat = (unsigned)cn[cls * CPC + i] * 90u + (unsigned)cls;
        keys[i] = ((unsigned long long)sb << 32) | (unsigned long long)(0xFFFFFFFFu - flat);
    }
    __syncthreads();

    int sel = 0;
    while (sel < SPC) {
        unsigned long long best = 0ull;
        for (int i = tid; i < cnt; i += 256) {
            unsigned long long k = keys[i];
            if (k > best) best = k;
        }
#pragma unroll
        for (int d = 32; d >= 1; d >>= 1) {
            unsigned long long o = __shfl_down(best, d, 64);
            if (o > best) best = o;
        }
        if ((tid & 63) == 0) red[tid >> 6] = best;
        __syncthreads();
        unsigned long long gbest = red[0];
        if (red[1] > gbest) gbest = red[1];
        if (red[2] > gbest) gbest = red[2];
        if (red[3] > gbest) gbest = red[3];
        if (gbest == 0ull) break;
        for (int i = tid; i < cnt; i += 256)
            if (keys[i] == gbest) { selsh = cb[i]; selidx_sh = i; }
        __syncthreads();
        float4 s = selsh;
        const int si = selidx_sh;
        const float sa = (s.z - s.x) * (s.w - s.y);
        if (tid == 0) {
            sbox[cls * SPC + sel] = s;
            unsigned int sb = (unsigned int)(gbest >> 32);
            sb ^= (sb >> 31) ? 0x80000000u : 0xFFFFFFFFu;
            sscore[cls * SPC + sel] = __uint_as_float(sb);
            skey[cls * SPC + sel] = gbest;
        }
        for (int i = tid; i < cnt; i += 256) {
            float4 b = cb[i];
            float xx1 = fmaxf(s.x, b.x), yy1 = fmaxf(s.y, b.y);
            float xx2 = fminf(s.z, b.z), yy2 = fminf(s.w, b.w);
            float inter = fmaxf(xx2 - xx1, 0.f) * fmaxf(yy2 - yy1, 0.f);
            float area = (b.z - b.x) * (b.w - b.y);
            if (3.f * inter > sa + area + 1e-9f || i == si) keys[i] = 0ull;
        }
        ++sel;
        __syncthreads();
    }
    if (tid == 0) scnt[cls] = sel;
}

// ---------------- 90-way merge ----------------
__global__ __launch_bounds__(128) void nms_merge(
    const float4* __restrict__ sbox, const float* __restrict__ sscore,
    const unsigned long long* __restrict__ skey, const int* __restrict__ scnt,
    float* __restrict__ out)
{
    const int tid = threadIdx.x;
    __shared__ int head[NCLS];
    __shared__ unsigned long long red[2];
    __shared__ int selc_sh;
    if (tid < NCLS) head[tid] = 0;
    __syncthreads();

    for (int k = 0; k < 100; ++k) {
        unsigned long long key = 0ull;
        if (tid < NCLS && head[tid] < scnt[tid]) key = skey[tid * SPC + head[tid]];
        unsigned long long mykey = key;
#pragma unroll
        for (int d = 32; d >= 1; d >>= 1) {
            unsigned long long o = __shfl_down(key, d, 64);
            if (o > key) key = o;
        }
        if ((tid & 63) == 0) red[tid >> 6] = key;
        if (tid == 0) selc_sh = -1;
        __syncthreads();
        unsigned long long gbest = red[0] > red[1] ? red[0] : red[1];
        if (gbest != 0ull && mykey == gbest) selc_sh = tid;
        __syncthreads();
        const int c = selc_sh;
        if (tid == 0) {
            if (c >= 0) {
                int h = head[c];
                float4 b = sbox[c * SPC + h];
                out[k * 4 + 0] = b.x; out[k * 4 + 1] = b.y;
                out[k * 4 + 2] = b.z; out[k * 4 + 3] = b.w;
                out[400 + k] = sscore[c * SPC + h];
                out[500 + k] = (float)(c + 1);
            } else {
                out[k * 4 + 0] = 0.f; out[k * 4 + 1] = 0.f;
                out[k * 4 + 2] = 0.f; out[k * 4 + 3] = 0.f;
                out[400 + k] = 0.f; out[500 + k] = 0.f;
            }
        }
        if (c >= 0 && tid == c) head[c]++;
        __syncthreads();
    }
}

// ------------------------------------------------------------------------
extern "C" void kernel_launch(void* const* d_in, const int* in_sizes, int n_in,
                              void* d_out, int out_size, void* d_ws, size_t ws_size,
                              hipStream_t stream)
{
    const float* bf    = (const float*)d_in[0];
    const float* props = (const float*)d_in[1];
    const float* W1    = (const float*)d_in[2];
    const float* b1    = (const float*)d_in[3];
    const float* W2    = (const float*)d_in[4];
    const float* b2    = (const float*)d_in[5];
    const float* Wc    = (const float*)d_in[6];
    const float* bc    = (const float*)d_in[7];
    const float* Wr    = (const float*)d_in[8];
    const float* br    = (const float*)d_in[9];
    const int*   ihp   = (const int*)d_in[10];
    const int*   iwp   = (const int*)d_in[11];
    float* ws  = (float*)d_ws;
    float* out = (float*)d_out;

    const size_t MN   = 2000ull * 1024ull;      // 2,048,000
    const size_t NLOG = 2000ull * 91ull;
    const size_t NREG = 2000ull * 364ull;
    const size_t NHEAD = 2000ull * 455ull;      // 910,000
    const size_t ws_floats = ws_size / 4;

    // ---- MFMA-path layout (float units); NEED formula unchanged ----
    const size_t BT1F = 1024ull * 12544ull / 2;   // 6,422,528 per bf16 array
    const size_t WT2F = 1024ull * 1024ull / 2;    // 524,288
    const size_t WHF  = 455ull * 1024ull / 2;     // 232,960
    const size_t NMSF = (size_t)NCLS * CPC * 6 + (size_t)NCLS * SPC * 7 + 256;
    const size_t PF   = 4 * MN;                   // 8,192,000 (covers 8*NHEAD too)
    const size_t NEED = 2 * BT1F + 2 * WT2F + 2 * WHF + 2 * MN + NHEAD + NMSF + PF + 64;

    if (ws_floats >= NEED) {
        // ===== bf16x3 MFMA path: R5 config + merged weight-prep launch =====
        unsigned short* BT1hi = (unsigned short*)ws;
        unsigned short* BT1lo = (unsigned short*)(ws + BT1F);
        unsigned short* WT2hi = (unsigned short*)(ws + 2 * BT1F);
        unsigned short* WT2lo = (unsigned short*)(ws + 2 * BT1F + WT2F);
        unsigned short* WHhi  = (unsigned short*)(ws + 2 * BT1F + 2 * WT2F);
        unsigned short* WHlo  = (unsigned short*)(ws + 2 * BT1F + 2 * WT2F + WHF);
        float* H1   = ws + 2 * BT1F + 2 * WT2F + 2 * WHF;
        float* H2   = H1 + MN;
        float* HEAD = H2 + MN;
        float* CBOX   = HEAD + NHEAD;
        float* CSCORE = CBOX + (size_t)NCLS * CPC * 4;
        int*   CN     = (int*)(CSCORE + (size_t)NCLS * CPC);
        float* SBOX   = (float*)(CN + (size_t)NCLS * CPC);
        float* SSCORE = SBOX + (size_t)NCLS * SPC * 4;
        unsigned long long* SKEY = (unsigned long long*)(SSCORE + (size_t)NCLS * SPC);
        int*   CCNT = (int*)(SKEY + (size_t)NCLS * SPC);
        int*   SCNT = CCNT + NCLS;
        float* P = (float*)(SCNT + NCLS + 64);    // +64 pad: 16B-align P for float4 combines

        // H1/H2 regions hold pre-split bf16 hi/lo (same byte footprint as fp32)
        unsigned short* H1hi = (unsigned short*)H1;
        unsigned short* H1lo = H1hi + MN;
        unsigned short* H2hi = (unsigned short*)H2;
        unsigned short* H2lo = H2hi + MN;

        // 0) merged weight prep: W1 + W2 + Wc/Wr transposes + CCNT zero, one launch
        prep_weights<<<7025, 256, 0, stream>>>(W1, BT1hi, BT1lo, W2, WT2hi, WT2lo,
                                               Wc, Wr, WHhi, WHlo, CCNT);
        // 1) GEMM1: 2000x12544x1024, z=4, 1024 blocks (4/CU)
        gemm_bf16x3_f32a<<<dim3(8, 32, 4), 256, 0, stream>>>(bf, BT1hi, BT1lo, P,
                                                             2000, 1024, 12544, 3136);
        combine_bias_split<<<(int)(MN / 4 / 256), 256, 0, stream>>>(P, b1, H1hi, H1lo,
                                                             (int)MN, 1024, 4, (int)MN, 1);
        // 2) GEMM2: 2000x1024x1024, z=4
        gemm_bf16x3_sa<<<dim3(8, 32, 4), 256, 0, stream>>>(H1hi, H1lo, WT2hi, WT2lo, P,
                                                           2000, 1024, 1024, 256);
        combine_bias_split<<<(int)(MN / 4 / 256), 256, 0, stream>>>(P, b2, H2hi, H2lo,
                                                             (int)MN, 1024, 4, (int)MN, 1);
        // 3) fused heads: 2000x1024x455, z=8
        gemm_bf16x3_sa<<<dim3(4, 32, 8), 256, 0, stream>>>(H2hi, H2lo, WHhi, WHlo, P,
                                                           2000, 455, 1024, 128);
        combine_head<<<(int)((NHEAD / 4 + 255) / 256), 256, 0, stream>>>(P, bc, br, HEAD,
                                                             (int)NHEAD, 8, (int)NHEAD);
        // 4) decode + compaction; 5) per-class NMS; 6) merge  (CCNT zeroed in prep)
        decode_compact<<<2000, 128, 0, stream>>>(HEAD, 455, HEAD + 91, 455,
                                                 (const float4*)props, ihp, iwp,
                                                 (float4*)CBOX, CSCORE, CN, CCNT);
        nms_class<<<NCLS, 256, 0, stream>>>((const float4*)CBOX, CSCORE, CN, CCNT,
                                            (float4*)SBOX, SSCORE, SKEY, SCNT);
        nms_merge<<<1, 128, 0, stream>>>((const float4*)SBOX, SSCORE, SKEY, SCNT, out);
        return;
    }

    // ================= fallback: fp32 vector path =================
    const size_t NMSF2 = (size_t)NCLS * CPC * 6 + (size_t)NCLS * SPC * 7 + 256;
    const size_t TAILF = 2 * MN + NLOG + NREG + NMSF2;
    int z1 = 2;
    if (ws_floats >= TAILF + 8 * MN) z1 = 8;
    else if (ws_floats >= TAILF + 4 * MN) z1 = 4;
    const size_t REUSE = (size_t)z1 * MN;
    int zh = (REUSE >= 8 * NREG) ? 8 : 4;

    float* P      = ws;
    float* H1     = P + REUSE;
    float* H2     = H1 + MN;
    float* LOG    = H2 + MN;
    float* BREG   = LOG + NLOG;
    float* CBOX   = BREG + NREG;
    float* CSCORE = CBOX + (size_t)NCLS * CPC * 4;
    int*   CN     = (int*)(CSCORE + (size_t)NCLS * CPC);
    float* SBOX   = (float*)(CN + (size_t)NCLS * CPC);
    float* SSCORE = SBOX + (size_t)NCLS * SPC * 4;
    unsigned long long* SKEY = (unsigned long long*)(SSCORE + (size_t)NCLS * SPC);
    int*   CCNT   = (int*)(SKEY + (size_t)NCLS * SPC);
    int*   SCNT   = CCNT + NCLS;

    gemm_f32<<<dim3(8, 16, z1), 256, 0, stream>>>(bf, W1, nullptr, P,
                                                  2000, 1024, 12544, 12544 / z1, 0);
    combine_bias_act<<<(int)((MN + 255) / 256), 256, 0, stream>>>(P, b1, H1,
                                                  (int)MN, 1024, z1, (int)MN, 1);
    gemm_f32<<<dim3(8, 16, 4), 256, 0, stream>>>(H1, W2, nullptr, P,
                                                 2000, 1024, 1024, 256, 0);
    combine_bias_act<<<(int)((MN + 255) / 256), 256, 0, stream>>>(P, b2, H2,
                                                 (int)MN, 1024, 4, (int)MN, 1);
    gemm_f32<<<dim3(1, 16, zh), 256, 0, stream>>>(H2, Wc, nullptr, P,
                                                  2000, 91, 1024, 1024 / zh, 0);
    combine_bias_act<<<(int)((NLOG + 255) / 256), 256, 0, stream>>>(P, bc, LOG,
                                                  (int)NLOG, 91, zh, (int)NLOG, 0);
    gemm_f32<<<dim3(3, 16, zh), 256, 0, stream>>>(H2, Wr, nullptr, P,
                                                  2000, 364, 1024, 1024 / zh, 0);
    combine_bias_act<<<(int)((NREG + 255) / 256), 256, 0, stream>>>(P, br, BREG,
                                                  (int)NREG, 364, zh, (int)NREG, 0);
    hipMemsetAsync(CCNT, 0, 2 * NCLS * sizeof(int), stream);
    decode_compact<<<2000, 128, 0, stream>>>(LOG, 91, BREG, 364,
                                             (const float4*)props, ihp, iwp,
                                             (float4*)CBOX, CSCORE, CN, CCNT);
    nms_class<<<NCLS, 256, 0, stream>>>((const float4*)CBOX, CSCORE, CN, CCNT,
                                        (float4*)SBOX, SSCORE, SKEY, SCNT);
    nms_merge<<<1, 128, 0, stream>>>((const float4*)SBOX, SSCORE, SKEY, SCNT, out);
}